// Round 1
// baseline (218.341 us; speedup 1.0000x reference)
//
#include <hip/hip_runtime.h>

// Problem constants
#define BINS 500
#define HID  512
#define INDD 128
#define PAIR_S 0.044194173824159216f   // 1/sqrt(512)

// d_out float offsets (outputs concatenated flat: out_mc, out_ih, micro, out_hic)
#define OFF_MC    0
#define OFF_IH    320000
#define OFF_MICRO 640000
#define OFF_HIC   32640000

// ws float offsets (needs ~2.5 MB of ws)
#define WS_H1   0          // 500*512 f32
#define WS_H    256000     // 500*512 f32
#define WS_HBAR 512000     // 100*512 f32
#define WS_MWT  563200     // bf16[128][512]  (micro_w^T)
#define WS_HWT  595968     // bf16[128][512]  (hic_w^T)
#define WS_W1CT 628736     // bf16[80][128]   (head_ih_w1 | head_mc_w, transposed)

typedef __bf16 bf16;
typedef bf16 bf16x4 __attribute__((ext_vector_type(4)));
typedef bf16 bf16x8 __attribute__((ext_vector_type(8)));
typedef float f32x4 __attribute__((ext_vector_type(4)));

__device__ __forceinline__ bf16x8 join8(bf16x4 lo, bf16x4 hi) {
  return __builtin_shufflevector(lo, hi, 0, 1, 2, 3, 4, 5, 6, 7);
}
__device__ __forceinline__ bf16x4 cvt4(float a, float b, float c, float d) {
  bf16x4 r; r[0] = (bf16)a; r[1] = (bf16)b; r[2] = (bf16)c; r[3] = (bf16)d; return r;
}
__device__ __forceinline__ bf16x4 pair4(float4 a, float4 b) {
  bf16x4 r;
  r[0] = (bf16)((a.x + b.x) * 0.5f + a.x * b.x * PAIR_S);
  r[1] = (bf16)((a.y + b.y) * 0.5f + a.y * b.y * PAIR_S);
  r[2] = (bf16)((a.z + b.z) * 0.5f + a.z * b.z * PAIR_S);
  r[3] = (bf16)((a.w + b.w) * 0.5f + a.w * b.w * PAIR_S);
  return r;
}

// ---------------------------------------------------------------------------
// Kernel 0: convert weights to bf16 transposed layouts in ws
// ---------------------------------------------------------------------------
__global__ void prep_weights(const float* __restrict__ micro_w,
                             const float* __restrict__ hic_w,
                             const float* __restrict__ w_ih1,
                             const float* __restrict__ w_mc,
                             float* __restrict__ ws) {
  int g = blockIdx.x * 256 + threadIdx.x;
  bf16* mwt = (bf16*)(ws + WS_MWT);
  bf16* hwt = (bf16*)(ws + WS_HWT);
  bf16* w1c = (bf16*)(ws + WS_W1CT);
  if (g < 65536) {                       // mwt[n][k] = micro_w[k][n]
    int n = g >> 9, k = g & 511;
    mwt[g] = (bf16)micro_w[k * INDD + n];
  } else if (g < 131072) {               // hwt[n][k] = hic_w[k][n]
    int gg = g - 65536;
    int n = gg >> 9, k = gg & 511;
    hwt[gg] = (bf16)hic_w[k * INDD + n];
  } else if (g < 131072 + 10240) {       // w1c[n][k]: n<64 -> w_ih1, n in {64,65} -> w_mc
    int gg = g - 131072;
    int n = gg >> 7, k = gg & 127;
    float v = 0.f;
    if (n < 64) v = w_ih1[k * 64 + n];
    else if (n < 66) v = w_mc[k * 2 + (n - 64)];
    w1c[gg] = (bf16)v;
  }
}

// ---------------------------------------------------------------------------
// Kernel 1/2: C = op(A @ B + bias), fp32 in/out, bf16 hi/lo split MFMA (3 prods)
// tile 64x64, 256 threads (4 waves, each 16 rows x 64 cols)
// ---------------------------------------------------------------------------
__global__ __launch_bounds__(256, 2)
void gemm_hilo(const float* __restrict__ A, const float* __restrict__ B,
               const float* __restrict__ bias, float* __restrict__ C,
               int M, int N, int K, int relu) {
  __shared__ float a_lds[64][36];
  __shared__ float bt_lds[64][36];
  const int t = threadIdx.x;
  const int w = t >> 6, l = t & 63;
  const int lr = l & 15, g = l >> 4;
  const int r0 = blockIdx.x * 64, n0 = blockIdx.y * 64;
  f32x4 acc[4] = {};
  for (int k0 = 0; k0 < K; k0 += 32) {
    { // stage A rows
      int row = t >> 2, kc = (t & 3) * 8;
      int gr = r0 + row; gr = gr < M ? gr : M - 1;
      const float* src = A + (size_t)gr * K + k0 + kc;
      *(float4*)&a_lds[row][kc]     = *(const float4*)src;
      *(float4*)&a_lds[row][kc + 4] = *(const float4*)(src + 4);
    }
    { // stage B^T
      int n = t & 63, ks = (t >> 6) * 8;
      const float* src = B + (size_t)(k0 + ks) * N + n0 + n;
      #pragma unroll
      for (int s = 0; s < 8; s++) bt_lds[n][ks + s] = src[(size_t)s * N];
    }
    __syncthreads();
    bf16x8 ahi, alo;
    {
      int row = w * 16 + lr;
      float4 u0 = *(const float4*)&a_lds[row][g * 8];
      float4 u1 = *(const float4*)&a_lds[row][g * 8 + 4];
      float v[8] = {u0.x, u0.y, u0.z, u0.w, u1.x, u1.y, u1.z, u1.w};
      #pragma unroll
      for (int e = 0; e < 8; e++) {
        bf16 h = (bf16)v[e];
        ahi[e] = h; alo[e] = (bf16)(v[e] - (float)h);
      }
    }
    #pragma unroll
    for (int fn = 0; fn < 4; fn++) {
      int col = fn * 16 + lr;
      float4 u0 = *(const float4*)&bt_lds[col][g * 8];
      float4 u1 = *(const float4*)&bt_lds[col][g * 8 + 4];
      float v[8] = {u0.x, u0.y, u0.z, u0.w, u1.x, u1.y, u1.z, u1.w};
      bf16x8 bhi, blo;
      #pragma unroll
      for (int e = 0; e < 8; e++) {
        bf16 h = (bf16)v[e];
        bhi[e] = h; blo[e] = (bf16)(v[e] - (float)h);
      }
      acc[fn] = __builtin_amdgcn_mfma_f32_16x16x32_bf16(ahi, bhi, acc[fn], 0, 0, 0);
      acc[fn] = __builtin_amdgcn_mfma_f32_16x16x32_bf16(ahi, blo, acc[fn], 0, 0, 0);
      acc[fn] = __builtin_amdgcn_mfma_f32_16x16x32_bf16(alo, bhi, acc[fn], 0, 0, 0);
    }
    __syncthreads();
  }
  #pragma unroll
  for (int fn = 0; fn < 4; fn++) {
    int col = n0 + fn * 16 + lr;
    float bv = bias[col];
    #pragma unroll
    for (int r = 0; r < 4; r++) {
      int row = r0 + w * 16 + g * 4 + r;
      float vv = acc[fn][r] + bv;
      if (relu) vv = fmaxf(vv, 0.f);
      if (row < M) C[(size_t)row * N + col] = vv;
    }
  }
}

// ---------------------------------------------------------------------------
// Kernel 3: hbar[a][k] = mean over 5 rows of h
// ---------------------------------------------------------------------------
__global__ void hbar_pool(const float* __restrict__ h, float* __restrict__ hbar) {
  int g = blockIdx.x * 256 + threadIdx.x;
  if (g >= 100 * HID) return;
  int a = g >> 9;
  int k = g & (HID - 1);
  const float* p = h + (size_t)(a * 5) * HID + k;
  hbar[g] = 0.2f * (p[0] + p[HID] + p[2 * HID] + p[3 * HID] + p[4 * HID]);
}

// ---------------------------------------------------------------------------
// Kernel 4: fused pair -> micro. Block = 16x16 (i,j) tile, 512 threads (8 waves,
// each 64 rows x 64 cols of the 256x128 output). micro written to d_out.
// ---------------------------------------------------------------------------
__global__ __launch_bounds__(512, 2)
void fused_micro(const float* __restrict__ h, const float* __restrict__ wsf,
                 const float* __restrict__ micro_b, float* __restrict__ out) {
  __shared__ float hi_lds[16][36];
  __shared__ float hj_lds[16][36];
  __shared__ bf16 pair_lds[256][36];
  __shared__ bf16 bt_lds[128][36];
  const int t = threadIdx.x;
  const int wv = t >> 6, l = t & 63;
  const int wm = wv >> 1, wn = wv & 1;
  const int lr = l & 15, g = l >> 4;
  const int i0 = blockIdx.x * 16, j0 = blockIdx.y * 16;
  const bf16* mwt = (const bf16*)(wsf + WS_MWT);
  f32x4 acc[4][4] = {};
  for (int kt = 0; kt < 16; kt++) {
    const int k0 = kt * 32;
    if (t < 128) {
      int row = t >> 3, c = (t & 7) * 4;
      int gi = i0 + row; gi = gi < BINS ? gi : BINS - 1;
      *(float4*)&hi_lds[row][c] = *(const float4*)(h + (size_t)gi * HID + k0 + c);
    } else if (t < 256) {
      int tt = t - 128;
      int row = tt >> 3, c = (tt & 7) * 4;
      int gj = j0 + row; gj = gj < BINS ? gj : BINS - 1;
      *(float4*)&hj_lds[row][c] = *(const float4*)(h + (size_t)gj * HID + k0 + c);
    } else {
      int tt = t - 256;
      #pragma unroll
      for (int rep = 0; rep < 2; rep++) {
        int chunk = tt * 2 + rep;          // 0..511
        int n = chunk >> 2, part = chunk & 3;
        bf16x8 v = *(const bf16x8*)(mwt + (size_t)n * HID + k0 + part * 8);
        *(bf16x4*)&bt_lds[n][part * 8]     = __builtin_shufflevector(v, v, 0, 1, 2, 3);
        *(bf16x4*)&bt_lds[n][part * 8 + 4] = __builtin_shufflevector(v, v, 4, 5, 6, 7);
      }
    }
    __syncthreads();
    { // pair tile: each thread does 16 elements (half a row)
      int m = t >> 1, half = t & 1;
      const float* pi = &hi_lds[m >> 4][half * 16];
      const float* pj = &hj_lds[m & 15][half * 16];
      #pragma unroll
      for (int c = 0; c < 2; c++) {
        float4 a0 = *(const float4*)(pi + c * 8);
        float4 a1 = *(const float4*)(pi + c * 8 + 4);
        float4 b0 = *(const float4*)(pj + c * 8);
        float4 b1 = *(const float4*)(pj + c * 8 + 4);
        *(bf16x4*)&pair_lds[m][half * 16 + c * 8]     = pair4(a0, b0);
        *(bf16x4*)&pair_lds[m][half * 16 + c * 8 + 4] = pair4(a1, b1);
      }
    }
    __syncthreads();
    bf16x8 af[4], bfr[4];
    #pragma unroll
    for (int fm = 0; fm < 4; fm++) {
      int row = wm * 64 + fm * 16 + lr;
      af[fm] = join8(*(const bf16x4*)&pair_lds[row][g * 8],
                     *(const bf16x4*)&pair_lds[row][g * 8 + 4]);
    }
    #pragma unroll
    for (int fn = 0; fn < 4; fn++) {
      int col = wn * 64 + fn * 16 + lr;
      bfr[fn] = join8(*(const bf16x4*)&bt_lds[col][g * 8],
                      *(const bf16x4*)&bt_lds[col][g * 8 + 4]);
    }
    #pragma unroll
    for (int fm = 0; fm < 4; fm++)
      #pragma unroll
      for (int fn = 0; fn < 4; fn++)
        acc[fm][fn] = __builtin_amdgcn_mfma_f32_16x16x32_bf16(af[fm], bfr[fn], acc[fm][fn], 0, 0, 0);
    __syncthreads();
  }
  #pragma unroll
  for (int fn = 0; fn < 4; fn++) {
    int n = wn * 64 + fn * 16 + lr;
    float mb = micro_b[n];
    #pragma unroll
    for (int fm = 0; fm < 4; fm++) {
      #pragma unroll
      for (int r = 0; r < 4; r++) {
        int m = wm * 64 + fm * 16 + g * 4 + r;
        int i = i0 + (m >> 4), j = j0 + (m & 15);
        if (i < BINS && j < BINS)
          out[(size_t)OFF_MICRO + (size_t)(i * BINS + j) * INDD + n] = acc[fm][fn][r] + mb;
      }
    }
  }
}

// ---------------------------------------------------------------------------
// Kernel 5: heads over the 400x400 crop. 256 pairs/block. GEMM (256x128)@(128x80)
// where cols 0..63 = head_ih_w1, 64..65 = head_mc_w. Second ih GEMM (K=64,N=2)
// done with per-lane partials + 16-lane butterfly.
// ---------------------------------------------------------------------------
__global__ __launch_bounds__(256, 2)
void heads_kernel(const float* __restrict__ micro, const float* __restrict__ wsf,
                  const float* __restrict__ b1, const float* __restrict__ w2,
                  const float* __restrict__ bmc, const float* __restrict__ b2,
                  float* __restrict__ out) {
  __shared__ bf16 a_lds[256][36];
  __shared__ bf16 bt_lds[80][132];
  const int t = threadIdx.x;
  const int wv = t >> 6, l = t & 63;
  const int lr = l & 15, g = l >> 4;
  const int mm0 = blockIdx.x * 256;
  const bf16* w1c = (const bf16*)(wsf + WS_W1CT);
  for (int c = t; c < 1280; c += 256) {   // stage all of w1c (80x128)
    int n = c >> 4, part = c & 15;
    bf16x8 v = *(const bf16x8*)(w1c + n * 128 + part * 8);
    *(bf16x4*)&bt_lds[n][part * 8]     = __builtin_shufflevector(v, v, 0, 1, 2, 3);
    *(bf16x4*)&bt_lds[n][part * 8 + 4] = __builtin_shufflevector(v, v, 4, 5, 6, 7);
  }
  f32x4 acc[4][5] = {};
  const int mm = mm0 + t;
  const int ii = 50 + mm / 400, jj = 50 + mm % 400;
  const float* arow = micro + (size_t)(ii * BINS + jj) * INDD;
  for (int kt = 0; kt < 4; kt++) {
    { // stage A: thread t loads its row's 32-k slice, converts to bf16
      const float* src = arow + kt * 32;
      #pragma unroll
      for (int c = 0; c < 4; c++) {
        float4 v0 = *(const float4*)(src + c * 8);
        float4 v1 = *(const float4*)(src + c * 8 + 4);
        *(bf16x4*)&a_lds[t][c * 8]     = cvt4(v0.x, v0.y, v0.z, v0.w);
        *(bf16x4*)&a_lds[t][c * 8 + 4] = cvt4(v1.x, v1.y, v1.z, v1.w);
      }
    }
    __syncthreads();
    bf16x8 af[4], bfr[5];
    #pragma unroll
    for (int fm = 0; fm < 4; fm++) {
      int row = wv * 64 + fm * 16 + lr;
      af[fm] = join8(*(const bf16x4*)&a_lds[row][g * 8],
                     *(const bf16x4*)&a_lds[row][g * 8 + 4]);
    }
    #pragma unroll
    for (int fn = 0; fn < 5; fn++) {
      int n = fn * 16 + lr;
      bfr[fn] = join8(*(const bf16x4*)&bt_lds[n][kt * 32 + g * 8],
                      *(const bf16x4*)&bt_lds[n][kt * 32 + g * 8 + 4]);
    }
    #pragma unroll
    for (int fm = 0; fm < 4; fm++)
      #pragma unroll
      for (int fn = 0; fn < 5; fn++)
        acc[fm][fn] = __builtin_amdgcn_mfma_f32_16x16x32_bf16(af[fm], bfr[fn], acc[fm][fn], 0, 0, 0);
    __syncthreads();
  }
  float w2a[4], w2b[4], b1v[4];
  #pragma unroll
  for (int fn = 0; fn < 4; fn++) {
    int q = fn * 16 + lr;
    w2a[fn] = w2[q * 2]; w2b[fn] = w2[q * 2 + 1]; b1v[fn] = b1[q];
  }
  float bm = (lr < 2) ? bmc[lr] : 0.f;
  float b2a = b2[0], b2bv = b2[1];
  #pragma unroll
  for (int fm = 0; fm < 4; fm++) {
    #pragma unroll
    for (int r = 0; r < 4; r++) {
      int m = wv * 64 + fm * 16 + g * 4 + r;
      float s0 = 0.f, s1 = 0.f;
      #pragma unroll
      for (int fn = 0; fn < 4; fn++) {
        float v = fmaxf(acc[fm][fn][r] + b1v[fn], 0.f);
        s0 += v * w2a[fn]; s1 += v * w2b[fn];
      }
      #pragma unroll
      for (int mk = 1; mk < 16; mk <<= 1) {
        s0 += __shfl_xor(s0, mk);
        s1 += __shfl_xor(s1, mk);
      }
      size_t mo = (size_t)(mm0 + m);
      if (lr == 0) {
        out[OFF_IH + mo * 2]     = s0 + b2a;
        out[OFF_IH + mo * 2 + 1] = s1 + b2bv;
      }
      if (lr < 2) out[OFF_MC + mo * 2 + lr] = acc[fm][4][r] + bm;
    }
  }
}

// ---------------------------------------------------------------------------
// Kernel 6: hic path from hbar (pooling factorizes!). 16x16 (a,b) tiles over
// the [10,90) crop; pair-from-hbar -> MFMA (K=512,N=128) -> 3-col head (VALU).
// ---------------------------------------------------------------------------
__global__ __launch_bounds__(256, 2)
void hic_kernel(const float* __restrict__ hbar, const float* __restrict__ wsf,
                const float* __restrict__ hicb, const float* __restrict__ whic,
                const float* __restrict__ bhic, float* __restrict__ out) {
  __shared__ float ha_lds[16][36];
  __shared__ float hb_lds[16][36];
  __shared__ bf16 pair_lds[256][36];
  __shared__ bf16 bt_lds[128][36];
  const int t = threadIdx.x;
  const int wv = t >> 6, l = t & 63;
  const int lr = l & 15, g = l >> 4;
  const int a0 = 10 + blockIdx.x * 16, b0 = 10 + blockIdx.y * 16;
  const bf16* hwt = (const bf16*)(wsf + WS_HWT);
  f32x4 acc[4][8] = {};
  for (int kt = 0; kt < 16; kt++) {
    const int k0 = kt * 32;
    if (t < 64) {
      int row = t >> 2, c = (t & 3) * 8;
      const float* src = hbar + (size_t)(a0 + row) * HID + k0 + c;
      *(float4*)&ha_lds[row][c]     = *(const float4*)src;
      *(float4*)&ha_lds[row][c + 4] = *(const float4*)(src + 4);
    } else if (t < 128) {
      int tt = t - 64;
      int row = tt >> 2, c = (tt & 3) * 8;
      const float* src = hbar + (size_t)(b0 + row) * HID + k0 + c;
      *(float4*)&hb_lds[row][c]     = *(const float4*)src;
      *(float4*)&hb_lds[row][c + 4] = *(const float4*)(src + 4);
    } else {
      int tt = t - 128;
      #pragma unroll
      for (int rep = 0; rep < 4; rep++) {
        int chunk = tt * 4 + rep;    // 0..511
        int n = chunk >> 2, part = chunk & 3;
        bf16x8 v = *(const bf16x8*)(hwt + (size_t)n * HID + k0 + part * 8);
        *(bf16x4*)&bt_lds[n][part * 8]     = __builtin_shufflevector(v, v, 0, 1, 2, 3);
        *(bf16x4*)&bt_lds[n][part * 8 + 4] = __builtin_shufflevector(v, v, 4, 5, 6, 7);
      }
    }
    __syncthreads();
    {
      int m = t;
      const float* pa = &ha_lds[m >> 4][0];
      const float* pb = &hb_lds[m & 15][0];
      #pragma unroll
      for (int c = 0; c < 4; c++) {
        float4 av0 = *(const float4*)(pa + c * 8);
        float4 av1 = *(const float4*)(pa + c * 8 + 4);
        float4 bv0 = *(const float4*)(pb + c * 8);
        float4 bv1 = *(const float4*)(pb + c * 8 + 4);
        *(bf16x4*)&pair_lds[m][c * 8]     = pair4(av0, bv0);
        *(bf16x4*)&pair_lds[m][c * 8 + 4] = pair4(av1, bv1);
      }
    }
    __syncthreads();
    bf16x8 af[4], bfr[8];
    #pragma unroll
    for (int fm = 0; fm < 4; fm++) {
      int row = wv * 64 + fm * 16 + lr;
      af[fm] = join8(*(const bf16x4*)&pair_lds[row][g * 8],
                     *(const bf16x4*)&pair_lds[row][g * 8 + 4]);
    }
    #pragma unroll
    for (int fn = 0; fn < 8; fn++) {
      int col = fn * 16 + lr;
      bfr[fn] = join8(*(const bf16x4*)&bt_lds[col][g * 8],
                      *(const bf16x4*)&bt_lds[col][g * 8 + 4]);
    }
    #pragma unroll
    for (int fm = 0; fm < 4; fm++)
      #pragma unroll
      for (int fn = 0; fn < 8; fn++)
        acc[fm][fn] = __builtin_amdgcn_mfma_f32_16x16x32_bf16(af[fm], bfr[fn], acc[fm][fn], 0, 0, 0);
    __syncthreads();
  }
  float wh0[8], wh1[8], wh2[8], hbv[8];
  #pragma unroll
  for (int fn = 0; fn < 8; fn++) {
    int n = fn * 16 + lr;
    wh0[fn] = whic[n * 3]; wh1[fn] = whic[n * 3 + 1]; wh2[fn] = whic[n * 3 + 2];
    hbv[fn] = hicb[n];
  }
  float bh0 = bhic[0], bh1 = bhic[1], bh2 = bhic[2];
  #pragma unroll
  for (int fm = 0; fm < 4; fm++) {
    #pragma unroll
    for (int r = 0; r < 4; r++) {
      int m = wv * 64 + fm * 16 + g * 4 + r;
      float s0 = 0.f, s1 = 0.f, s2 = 0.f;
      #pragma unroll
      for (int fn = 0; fn < 8; fn++) {
        float v = acc[fm][fn][r] + hbv[fn];
        s0 += v * wh0[fn]; s1 += v * wh1[fn]; s2 += v * wh2[fn];
      }
      #pragma unroll
      for (int mk = 1; mk < 16; mk <<= 1) {
        s0 += __shfl_xor(s0, mk);
        s1 += __shfl_xor(s1, mk);
        s2 += __shfl_xor(s2, mk);
      }
      if (lr == 0) {
        int aa = a0 + (m >> 4) - 10, bb = b0 + (m & 15) - 10;
        size_t o = (size_t)OFF_HIC + (size_t)(aa * 80 + bb) * 3;
        out[o] = s0 + bh0; out[o + 1] = s1 + bh1; out[o + 2] = s2 + bh2;
      }
    }
  }
}

// ---------------------------------------------------------------------------
extern "C" void kernel_launch(void* const* d_in, const int* in_sizes, int n_in,
                              void* d_out, int out_size, void* d_ws, size_t ws_size,
                              hipStream_t stream) {
  (void)in_sizes; (void)n_in; (void)out_size; (void)ws_size;
  const float* x    = (const float*)d_in[0];
  const float* pw1  = (const float*)d_in[1];
  const float* pb1  = (const float*)d_in[2];
  const float* pw2  = (const float*)d_in[3];
  const float* pb2  = (const float*)d_in[4];
  const float* mw   = (const float*)d_in[5];
  const float* mb   = (const float*)d_in[6];
  const float* hw   = (const float*)d_in[7];
  const float* hb   = (const float*)d_in[8];
  const float* wmc  = (const float*)d_in[9];
  const float* bmc  = (const float*)d_in[10];
  const float* wih1 = (const float*)d_in[11];
  const float* bih1 = (const float*)d_in[12];
  const float* wih2 = (const float*)d_in[13];
  const float* bih2 = (const float*)d_in[14];
  const float* whic = (const float*)d_in[15];
  const float* bhic = (const float*)d_in[16];
  float* out = (float*)d_out;
  float* ws  = (float*)d_ws;

  prep_weights<<<552, 256, 0, stream>>>(mw, hw, wih1, wmc, ws);
  gemm_hilo<<<dim3(8, 8), 256, 0, stream>>>(x, pw1, pb1, ws + WS_H1, 500, 512, 1024, 1);
  gemm_hilo<<<dim3(8, 8), 256, 0, stream>>>(ws + WS_H1, pw2, pb2, ws + WS_H, 500, 512, 512, 0);
  hbar_pool<<<200, 256, 0, stream>>>(ws + WS_H, ws + WS_HBAR);
  fused_micro<<<dim3(32, 32), 512, 0, stream>>>(ws + WS_H, ws, mb, out);
  heads_kernel<<<625, 256, 0, stream>>>(out + OFF_MICRO, ws, bih1, wih2, bmc, bih2, out);
  hic_kernel<<<dim3(5, 5), 256, 0, stream>>>(ws + WS_HBAR, ws, hb, whic, bhic, out);
}